// Round 4
// baseline (350.784 us; speedup 1.0000x reference)
//
#include <hip/hip_runtime.h>
#include <hip/hip_cooperative_groups.h>
namespace cg = cooperative_groups;

// Problem: b=4, c=64, h=w=128, ks=3, N=9, offset ch=18, oc=64. Padded HP=130.
#define BATCH 4
#define CH    64
#define HH    128
#define WW    128
#define HW    (HH*WW)
#define HP    130
#define NOFF  18
#define OC    64

typedef _Float16 half8 __attribute__((ext_vector_type(8)));
typedef _Float16 half4 __attribute__((ext_vector_type(4)));
typedef float f32x4 __attribute__((ext_vector_type(4)));

// ws layout (bytes):
//   wf  @ 0      : 36864 f16 (main A-frags)    pf @ 73728: 18432 f16
//   x0t @ 110592 : 4*130*130*64 f16 (padded NHWC, zero ring)
//   x1t @ 8763392: same                        total 17416192 B
#define WF_OFF  0
#define PF_OFF  73728
#define X0T_OFF 110592
#define X1T_OFF 8763392

// ===========================================================================
// R4: single cooperative kernel. 1024 blocks x 256 thr = exactly 4 blocks/CU
// x 256 CUs (LDS 40320 B x4 = 161280 <= 163840). Prep units (2280: 2048
// transpose half-rows, 16 ring-zeros, 216 frag chunks) strided over blocks;
// grid.sync() replaces the prep->deform kernel boundary (saves full device
// drain + second dispatch ramp); then each block runs TWO deform strips
// (local, local+128) preserving the XCD band swizzle. Phase bodies verbatim
// R3 (best measured: 113.5 us).
// ===========================================================================
__global__ __launch_bounds__(256, 4) void fused_all(
    const float* __restrict__ x0, const float* __restrict__ x1,
    const float* __restrict__ cw, const float* __restrict__ pw,
    const float* __restrict__ pb,
    _Float16* __restrict__ x0t, _Float16* __restrict__ x1t,
    _Float16* __restrict__ wf, _Float16* __restrict__ pf,
    float* __restrict__ out) {
  __shared__ __align__(16) _Float16 btile[2 * 18 * 64 * 8];   // 36864 B, multi-aliased
  __shared__ __align__(16) _Float16 wtab[288 * 4];            // 2304 B
  __shared__ unsigned ctab[288];                              // 1152 B
  int tid = threadIdx.x, blk = blockIdx.x;

  // ===== PREP phase: units blk, blk+1024, blk+2048 =====
  for (int u = blk; u < 2280; u += 1024) {
    if (u < 2048) {
      float* tile = (float*)btile;          // 64*66 f32 = 16896 B alias into btile
      int jh = u & 1, i = (u >> 1) & 127, b = (u >> 8) & 3, which = u >> 10;
      const float* src = which ? x1 : x0;
      _Float16* dst = which ? x1t : x0t;
#pragma unroll
      for (int it = 0; it < 4; it++) {
        int idx = it * 256 + tid;           // 1024 float4 = 64c x 64j
        int c = idx >> 4, j4 = (idx & 15) << 2;
        float4 v = *(const float4*)(src + (size_t)(b * CH + c) * HW + i * WW + jh * 64 + j4);
        *(float4*)&tile[c * 66 + j4] = v;
      }
      __syncthreads();
      int jl = tid >> 2, cq = (tid & 3) << 4;
      _Float16* dp = dst + ((size_t)(b * HP + i + 1) * HP + (jh * 64 + jl + 1)) * CH + cq;
#pragma unroll
      for (int h = 0; h < 2; h++) {
        half8 v;
#pragma unroll
        for (int cc = 0; cc < 8; cc++) v[cc] = (_Float16)tile[(cq + h * 8 + cc) * 66 + jl];
        *(half8*)(dp + h * 8) = v;
      }
      if (tid < 8) {                        // ring column jo=0 (jh0) / jo=129 (jh1)
        int jo = jh ? (HP - 1) : 0;
        _Float16* zp = dst + ((size_t)(b * HP + i + 1) * HP + jo) * CH + tid * 8;
        int4 z = {0, 0, 0, 0};
        *(int4*)zp = z;
      }
      __syncthreads();                      // tile reused by next unit
    } else if (u < 2064) {
      int z = u - 2048;
      int which = z >> 3, b = (z >> 1) & 3, top = z & 1;
      _Float16* dst = (which ? x1t : x0t) + ((size_t)(b * HP + top * (HP - 1)) * HP) * CH;
      int4 zz = {0, 0, 0, 0};
      for (int e = tid; e < 1040; e += 256) *(int4*)((char*)dst + e * 16) = zz;
    } else {
      int gid = (u - 2064) * 256 + tid;     // 216*256 = 36864 + 18432
      if (gid < 36864) {
        int j = gid & 7, lane = (gid >> 3) & 63, mt = (gid >> 9) & 3, s = gid >> 11;
        int oc = mt * 16 + (lane & 15);
        int t = s * 32 + (lane >> 4) * 8 + j;
        int k = t >> 6, c = t & 63;
        wf[gid] = (_Float16)cw[(oc * CH + c) * 9 + k];
      } else {
        int g = gid - 36864;
        int j = g & 7, lane = (g >> 3) & 63, mt = (g >> 9) & 1, s = g >> 10;
        int o = mt * 16 + (lane & 15);
        int t = s * 32 + (lane >> 4) * 8 + j;
        int k = t >> 6, c = t & 63;
        pf[g] = (o < NOFF) ? (_Float16)pw[(o * CH + c) * 9 + k] : (_Float16)0.f;
      }
    }
  }

  __threadfence();
  cg::this_grid().sync();                   // replaces prep->deform kernel boundary

  // ===== DEFORM phase: two 32-px strips per block =====
  float* offs = (float*)&btile[12288];      // bytes [24576,27136): dead during ph0/1
  int xcd = blk & 7, local = blk >> 3;      // local 0..127
#pragma unroll 1
  for (int hs = 0; hs < 2; hs++) {
    if (hs) __syncthreads();                // btile: strip0 ph3 reads vs strip1 ph0 writes
    int strip = xcd * 256 + local + hs * 128;   // same XCD band as R3
    int jq2 = strip & 3, i = (strip >> 2) & 127, b = strip >> 9;
    int j0 = jq2 * 32;
    const _Float16* x0b = x0t + (size_t)b * HP * HP * CH;
    const _Float16* x1b = x1t + (size_t)b * HP * HP * CH;

    // ---- Phase 0: stage x1t patch rows i..i+2, cols j0..j0+33 ----
    {
#pragma unroll
      for (int it = 0; it < 4; it++) {
        int e = it * 256 + tid;             // 816 half8 chunks = 3*34*8
        if (e < 816) {
          int r = e / 272, rem = e - r * 272;
          int col = rem >> 3, cg8 = rem & 7;
          half8 v = *(const half8*)(x1b + ((size_t)(i + r) * HP + (j0 + col)) * CH + cg8 * 8);
          *(half8*)&btile[(r * 34 + col) * 72 + cg8 * 8] = v;
        }
      }
    }
    __syncthreads();

    // ---- Phase 1: offset GEMM (M=32 padded from 18, K=576), A-reuse over nt ----
    {
      int lane = tid & 63, w = tid >> 6;
      if (w < 2) {                          // wave w owns m-tile w; waves 2-3 idle
        int p = lane & 15, q = lane >> 4;
        const half8* pfv = (const half8*)pf;
        f32x4 acc0 = {0.f, 0.f, 0.f, 0.f}, acc1 = {0.f, 0.f, 0.f, 0.f};
#pragma unroll 3
        for (int s = 0; s < 18; s++) {
          int u = 4 * s + q, k = u >> 3, c0 = (u & 7) << 3;  // t = s*32+q*8 -> (k,c)
          int ki = (k * 86) >> 8, kj = k - ki * 3;           // k/3, k%3 for k<9
          half8 a = pfv[(s * 2 + w) * 64 + lane];
          half8 b0 = *(const half8*)&btile[(ki * 34 + p + kj) * 72 + c0];
          half8 b1 = *(const half8*)&btile[(ki * 34 + 16 + p + kj) * 72 + c0];
          acc0 = __builtin_amdgcn_mfma_f32_16x16x32_f16(a, b0, acc0, 0, 0, 0);
          acc1 = __builtin_amdgcn_mfma_f32_16x16x32_f16(a, b1, acc1, 0, 0, 0);
        }
        int col = lane & 15, quad = lane >> 4;
#pragma unroll
        for (int r = 0; r < 4; r++) {
          int o = w * 16 + quad * 4 + r;
          if (o < NOFF) {
            float bias = pb[o];
            offs[col * 20 + o] = acc0[r] + bias;
            offs[(16 + col) * 20 + o] = acc1[r] + bias;
          }
        }
      }
    }
    __syncthreads();

    // ---- Phase 1.5: build interp weight/coord tables, one item per (px,k) ----
    {
      auto build = [&](int px, int k) {
        float ox = offs[px * 20 + k];
        float oy = offs[px * 20 + k + 9];
        int ki = (k * 11) >> 5, kj = k - ki * 3;             // k/3, k%3 for k<9
        float pxr = (float)(i + ki) + ox;                    // padded coords
        float pyr = (float)(j0 + px + kj) + oy;
        float fx = floorf(pxr), fy = floorf(pyr);
        float qltx = fminf(fmaxf(fx, 0.f), 129.f);
        float qlty = fminf(fmaxf(fy, 0.f), 129.f);
        float qrbx = fminf(fmaxf(fx + 1.f, 0.f), 129.f);
        float qrby = fminf(fmaxf(fy + 1.f, 0.f), 129.f);
        float pxc = fminf(fmaxf(pxr, 0.f), 129.f);
        float pyc = fminf(fmaxf(pyr, 0.f), 129.f);
        half4 wv;
        wv[0] = (_Float16)((1.f + qltx - pxc) * (1.f + qlty - pyc));  // lt
        wv[1] = (_Float16)((1.f - qrbx + pxc) * (1.f - qrby + pyc));  // rb
        wv[2] = (_Float16)((1.f + qltx - pxc) * (1.f - qrby + pyc));  // lb
        wv[3] = (_Float16)((1.f - qrbx + pxc) * (1.f + qlty - pyc));  // rt
        *(half4*)&wtab[(px * 9 + k) * 4] = wv;
        ctab[px * 9 + k] = (unsigned)(int)qltx | ((unsigned)(int)qlty << 8) |
                           ((unsigned)(int)qrbx << 16) | ((unsigned)(int)qrby << 24);
      };
      build(tid >> 3, tid & 7);             // items k=0..7 for all 32 px
      if (tid < 32) build(tid, 8);          // items k=8
    }
    __syncthreads();

    // ---- Phase 2: coalesced gather + table-driven interp -> frag btile ----
    {
      int cg8 = tid & 7, px = tid >> 3;     // 32 px x 8 channel-chunks
      int c0 = cg8 * 8;
      int nt = px >> 4, pxl = px & 15, kgq = cg8 & 3, sh = cg8 >> 2;
      _Float16* wslot = &btile[(((nt * 18) * 4 + kgq) * 16 + pxl) * 8];
      const _Float16* xb0 = x0b + c0;
#pragma unroll
      for (int k = 0; k < 9; k++) {
        half4 wv = *(const half4*)&wtab[(px * 9 + k) * 4];   // broadcast across cg
        unsigned cc = ctab[px * 9 + k];
        int ltx = cc & 255, lty = (cc >> 8) & 255;
        int rbx = (cc >> 16) & 255, rby = cc >> 24;
        const _Float16* rowl = xb0 + ltx * (HP * CH);
        const _Float16* rowr = xb0 + rbx * (HP * CH);
        half8 vlt = *(const half8*)(rowl + lty * CH);
        half8 vlb = *(const half8*)(rowl + rby * CH);
        half8 vrb = *(const half8*)(rowr + rby * CH);
        half8 vrt = *(const half8*)(rowr + lty * CH);
        half8 f = vlt * wv[0] + vrb * wv[1] + vlb * wv[2] + vrt * wv[3];
        int s = k * 2 + sh;                 // t = k*64 + c0 + jj -> frag (s,kgq,pxl)
        *(half8*)(wslot + s * 512) = f;     // 512 halfs per s-step
      }
    }
    __syncthreads();

    // ---- Phase 3: main GEMM, D[oc][px], M=64, K=576, A-reuse over nt ----
    {
      int lane = tid & 63, w = tid >> 6;    // wave w = m-tile 0..3
      f32x4 acc0 = {0.f, 0.f, 0.f, 0.f}, acc1 = {0.f, 0.f, 0.f, 0.f};
      const half8* wfv = (const half8*)wf;
      const half8* bt0 = (const half8*)&btile[0];
      const half8* bt1 = (const half8*)&btile[18 * 512];
#pragma unroll 6
      for (int s = 0; s < 18; s++) {
        half8 a = wfv[(s * 4 + w) * 64 + lane];
        acc0 = __builtin_amdgcn_mfma_f32_16x16x32_f16(a, bt0[s * 64 + lane], acc0, 0, 0, 0);
        acc1 = __builtin_amdgcn_mfma_f32_16x16x32_f16(a, bt1[s * 64 + lane], acc1, 0, 0, 0);
      }
      int col = lane & 15, quad = lane >> 4;
#pragma unroll
      for (int r = 0; r < 4; r++) {
        int oc = w * 16 + quad * 4 + r;
        float* orow = out + ((size_t)(b * OC + oc) * HH + i) * WW;
        orow[j0 + col] = acc0[r];
        orow[j0 + 16 + col] = acc1[r];
      }
    }
  }
}

// ===========================================================================
// Fallback two-kernel path (verbatim R3), used only if cooperative launch is
// rejected synchronously.
// ===========================================================================
__global__ __launch_bounds__(256) void prep_all(
    const float* __restrict__ x0, const float* __restrict__ x1,
    const float* __restrict__ cw, const float* __restrict__ pw,
    _Float16* __restrict__ x0t, _Float16* __restrict__ x1t,
    _Float16* __restrict__ wf, _Float16* __restrict__ pf) {
  int blk = blockIdx.x, tid = threadIdx.x;
  if (blk < 2048) {
    __shared__ float tile[64 * 66];
    int jh = blk & 1, i = (blk >> 1) & 127, b = (blk >> 8) & 3, which = blk >> 10;
    const float* src = which ? x1 : x0;
    _Float16* dst = which ? x1t : x0t;
#pragma unroll
    for (int it = 0; it < 4; it++) {
      int idx = it * 256 + tid;
      int c = idx >> 4, j4 = (idx & 15) << 2;
      float4 v = *(const float4*)(src + (size_t)(b * CH + c) * HW + i * WW + jh * 64 + j4);
      *(float4*)&tile[c * 66 + j4] = v;
    }
    __syncthreads();
    int jl = tid >> 2, cq = (tid & 3) << 4;
    _Float16* dp = dst + ((size_t)(b * HP + i + 1) * HP + (jh * 64 + jl + 1)) * CH + cq;
#pragma unroll
    for (int h = 0; h < 2; h++) {
      half8 v;
#pragma unroll
      for (int cc = 0; cc < 8; cc++) v[cc] = (_Float16)tile[(cq + h * 8 + cc) * 66 + jl];
      *(half8*)(dp + h * 8) = v;
    }
    if (tid < 8) {
      int jo = jh ? (HP - 1) : 0;
      _Float16* zp = dst + ((size_t)(b * HP + i + 1) * HP + jo) * CH + tid * 8;
      int4 z = {0, 0, 0, 0};
      *(int4*)zp = z;
    }
  } else if (blk < 2064) {
    int z = blk - 2048;
    int which = z >> 3, b = (z >> 1) & 3, top = z & 1;
    _Float16* dst = (which ? x1t : x0t) + ((size_t)(b * HP + top * (HP - 1)) * HP) * CH;
    int4 zz = {0, 0, 0, 0};
    for (int e = tid; e < 1040; e += 256) *(int4*)((char*)dst + e * 16) = zz;
  } else {
    int gid = (blk - 2064) * 256 + tid;
    if (gid < 36864) {
      int j = gid & 7, lane = (gid >> 3) & 63, mt = (gid >> 9) & 3, s = gid >> 11;
      int oc = mt * 16 + (lane & 15);
      int t = s * 32 + (lane >> 4) * 8 + j;
      int k = t >> 6, c = t & 63;
      wf[gid] = (_Float16)cw[(oc * CH + c) * 9 + k];
    } else {
      int g = gid - 36864;
      int j = g & 7, lane = (g >> 3) & 63, mt = (g >> 9) & 1, s = g >> 10;
      int o = mt * 16 + (lane & 15);
      int t = s * 32 + (lane >> 4) * 8 + j;
      int k = t >> 6, c = t & 63;
      pf[g] = (o < NOFF) ? (_Float16)pw[(o * CH + c) * 9 + k] : (_Float16)0.f;
    }
  }
}

__global__ __launch_bounds__(256, 4) void deform_all(
    const _Float16* __restrict__ x0t, const _Float16* __restrict__ x1t,
    const _Float16* __restrict__ pf, const float* __restrict__ pb,
    const _Float16* __restrict__ wf, float* __restrict__ out) {
  __shared__ __align__(16) _Float16 btile[2 * 18 * 64 * 8];
  __shared__ __align__(16) _Float16 wtab[288 * 4];
  __shared__ unsigned ctab[288];
  float* offs = (float*)&btile[12288];

  int xcd = blockIdx.x & 7, local = blockIdx.x >> 3;
  int strip = xcd * 256 + local;
  int jq2 = strip & 3, i = (strip >> 2) & 127, b = strip >> 9;
  int j0 = jq2 * 32;
  int tid = threadIdx.x;
  const _Float16* x0b = x0t + (size_t)b * HP * HP * CH;
  const _Float16* x1b = x1t + (size_t)b * HP * HP * CH;

  {
#pragma unroll
    for (int it = 0; it < 4; it++) {
      int e = it * 256 + tid;
      if (e < 816) {
        int r = e / 272, rem = e - r * 272;
        int col = rem >> 3, cg8 = rem & 7;
        half8 v = *(const half8*)(x1b + ((size_t)(i + r) * HP + (j0 + col)) * CH + cg8 * 8);
        *(half8*)&btile[(r * 34 + col) * 72 + cg8 * 8] = v;
      }
    }
  }
  __syncthreads();

  {
    int lane = tid & 63, w = tid >> 6;
    if (w < 2) {
      int p = lane & 15, q = lane >> 4;
      const half8* pfv = (const half8*)pf;
      f32x4 acc0 = {0.f, 0.f, 0.f, 0.f}, acc1 = {0.f, 0.f, 0.f, 0.f};
#pragma unroll 3
      for (int s = 0; s < 18; s++) {
        int u = 4 * s + q, k = u >> 3, c0 = (u & 7) << 3;
        int ki = (k * 86) >> 8, kj = k - ki * 3;
        half8 a = pfv[(s * 2 + w) * 64 + lane];
        half8 b0 = *(const half8*)&btile[(ki * 34 + p + kj) * 72 + c0];
        half8 b1 = *(const half8*)&btile[(ki * 34 + 16 + p + kj) * 72 + c0];
        acc0 = __builtin_amdgcn_mfma_f32_16x16x32_f16(a, b0, acc0, 0, 0, 0);
        acc1 = __builtin_amdgcn_mfma_f32_16x16x32_f16(a, b1, acc1, 0, 0, 0);
      }
      int col = lane & 15, quad = lane >> 4;
#pragma unroll
      for (int r = 0; r < 4; r++) {
        int o = w * 16 + quad * 4 + r;
        if (o < NOFF) {
          float bias = pb[o];
          offs[col * 20 + o] = acc0[r] + bias;
          offs[(16 + col) * 20 + o] = acc1[r] + bias;
        }
      }
    }
  }
  __syncthreads();

  {
    auto build = [&](int px, int k) {
      float ox = offs[px * 20 + k];
      float oy = offs[px * 20 + k + 9];
      int ki = (k * 11) >> 5, kj = k - ki * 3;
      float pxr = (float)(i + ki) + ox;
      float pyr = (float)(j0 + px + kj) + oy;
      float fx = floorf(pxr), fy = floorf(pyr);
      float qltx = fminf(fmaxf(fx, 0.f), 129.f);
      float qlty = fminf(fmaxf(fy, 0.f), 129.f);
      float qrbx = fminf(fmaxf(fx + 1.f, 0.f), 129.f);
      float qrby = fminf(fmaxf(fy + 1.f, 0.f), 129.f);
      float pxc = fminf(fmaxf(pxr, 0.f), 129.f);
      float pyc = fminf(fmaxf(pyr, 0.f), 129.f);
      half4 wv;
      wv[0] = (_Float16)((1.f + qltx - pxc) * (1.f + qlty - pyc));
      wv[1] = (_Float16)((1.f - qrbx + pxc) * (1.f - qrby + pyc));
      wv[2] = (_Float16)((1.f + qltx - pxc) * (1.f - qrby + pyc));
      wv[3] = (_Float16)((1.f - qrbx + pxc) * (1.f + qlty - pyc));
      *(half4*)&wtab[(px * 9 + k) * 4] = wv;
      ctab[px * 9 + k] = (unsigned)(int)qltx | ((unsigned)(int)qlty << 8) |
                         ((unsigned)(int)qrbx << 16) | ((unsigned)(int)qrby << 24);
    };
    build(tid >> 3, tid & 7);
    if (tid < 32) build(tid, 8);
  }
  __syncthreads();

  {
    int cg8 = tid & 7, px = tid >> 3;
    int c0 = cg8 * 8;
    int nt = px >> 4, pxl = px & 15, kgq = cg8 & 3, sh = cg8 >> 2;
    _Float16* wslot = &btile[(((nt * 18) * 4 + kgq) * 16 + pxl) * 8];
    const _Float16* xb0 = x0b + c0;
#pragma unroll
    for (int k = 0; k < 9; k++) {
      half4 wv = *(const half4*)&wtab[(px * 9 + k) * 4];
      unsigned cc = ctab[px * 9 + k];
      int ltx = cc & 255, lty = (cc >> 8) & 255;
      int rbx = (cc >> 16) & 255, rby = cc >> 24;
      const _Float16* rowl = xb0 + ltx * (HP * CH);
      const _Float16* rowr = xb0 + rbx * (HP * CH);
      half8 vlt = *(const half8*)(rowl + lty * CH);
      half8 vlb = *(const half8*)(rowl + rby * CH);
      half8 vrb = *(const half8*)(rowr + rby * CH);
      half8 vrt = *(const half8*)(rowr + lty * CH);
      half8 f = vlt * wv[0] + vrb * wv[1] + vlb * wv[2] + vrt * wv[3];
      int s = k * 2 + sh;
      *(half8*)(wslot + s * 512) = f;
    }
  }
  __syncthreads();

  {
    int lane = tid & 63, w = tid >> 6;
    f32x4 acc0 = {0.f, 0.f, 0.f, 0.f}, acc1 = {0.f, 0.f, 0.f, 0.f};
    const half8* wfv = (const half8*)wf;
    const half8* bt0 = (const half8*)&btile[0];
    const half8* bt1 = (const half8*)&btile[18 * 512];
#pragma unroll 6
    for (int s = 0; s < 18; s++) {
      half8 a = wfv[(s * 4 + w) * 64 + lane];
      acc0 = __builtin_amdgcn_mfma_f32_16x16x32_f16(a, bt0[s * 64 + lane], acc0, 0, 0, 0);
      acc1 = __builtin_amdgcn_mfma_f32_16x16x32_f16(a, bt1[s * 64 + lane], acc1, 0, 0, 0);
    }
    int col = lane & 15, quad = lane >> 4;
#pragma unroll
    for (int r = 0; r < 4; r++) {
      int oc = w * 16 + quad * 4 + r;
      float* orow = out + ((size_t)(b * OC + oc) * HH + i) * WW;
      orow[j0 + col] = acc0[r];
      orow[j0 + 16 + col] = acc1[r];
    }
  }
}

// ---------------------------------------------------------------------------
extern "C" void kernel_launch(void* const* d_in, const int* in_sizes, int n_in,
                              void* d_out, int out_size, void* d_ws, size_t ws_size,
                              hipStream_t stream) {
  const float* x0 = (const float*)d_in[0];
  const float* x1 = (const float*)d_in[1];
  const float* pw = (const float*)d_in[2];
  const float* pb = (const float*)d_in[3];
  const float* cw = (const float*)d_in[4];
  float* out = (float*)d_out;

  _Float16* wfrag  = (_Float16*)((char*)d_ws + WF_OFF);
  _Float16* pwfrag = (_Float16*)((char*)d_ws + PF_OFF);
  _Float16* x0t    = (_Float16*)((char*)d_ws + X0T_OFF);
  _Float16* x1t    = (_Float16*)((char*)d_ws + X1T_OFF);

  void* args[] = {(void*)&x0, (void*)&x1, (void*)&cw, (void*)&pw, (void*)&pb,
                  (void*)&x0t, (void*)&x1t, (void*)&wfrag, (void*)&pwfrag,
                  (void*)&out};
  hipError_t err = hipLaunchCooperativeKernel((const void*)fused_all,
                                              dim3(1024), dim3(256), args, 0, stream);
  if (err != hipSuccess) {
    // Fallback: proven two-kernel path (R3).
    prep_all<<<dim3(2280), dim3(256), 0, stream>>>(x0, x1, cw, pw, x0t, x1t, wfrag, pwfrag);
    deform_all<<<dim3(2048), dim3(256), 0, stream>>>(x0t, x1t, pwfrag, pb, wfrag, out);
  }
}

// Round 5
// 114.161 us; speedup vs baseline: 3.0727x; 3.0727x over previous
//
#include <hip/hip_runtime.h>

// Problem: b=4, c=64, h=w=128, ks=3, N=9, offset ch=18, oc=64. Padded HP=130.
#define BATCH 4
#define CH    64
#define HH    128
#define WW    128
#define HW    (HH*WW)
#define HP    130
#define NOFF  18
#define OC    64

typedef _Float16 half8 __attribute__((ext_vector_type(8)));
typedef _Float16 half4 __attribute__((ext_vector_type(4)));
typedef float f32x4 __attribute__((ext_vector_type(4)));

// ws layout (bytes):
//   wf  @ 0      : 36864 f16 (main A-frags)    pf @ 73728: 18432 f16
//   x0t @ 110592 : 4*130*130*64 f16 (padded NHWC, zero ring)
//   x1t @ 8763392: same                        total 17416192 B
#define WF_OFF  0
#define PF_OFF  73728
#define X0T_OFF 110592
#define X1T_OFF 8763392

// ---------------------------------------------------------------------------
// Kernel A: blocks 0..2047 transpose half-rows NCHW f32 -> padded NHWC f16;
// 2048..2063 zero ring rows; 2064..2279 A-fragments (k-major t = k*64+c).
// R5 fix: transpose tile stride 66 -> 65 floats. At 66 (even), both the
// float4 writes (bank = (2c+j4)%32) and the scalar column reads
// (bank = (2(cq+cc)+jl)%32 with cq*2%32=0) hit 16 banks x 4 lanes = 4-way
// conflict (1.58x per m136). At 65 (odd) both become <=2-way (free).
// R4's fused dispatch surfaced SQ_LDS_BANK_CONFLICT=5.7M; this tile is the
// only >=4-way pattern in the pipeline.
// ---------------------------------------------------------------------------
__global__ __launch_bounds__(256) void prep_all(
    const float* __restrict__ x0, const float* __restrict__ x1,
    const float* __restrict__ cw, const float* __restrict__ pw,
    _Float16* __restrict__ x0t, _Float16* __restrict__ x1t,
    _Float16* __restrict__ wf, _Float16* __restrict__ pf) {
  int blk = blockIdx.x, tid = threadIdx.x;
  if (blk < 2048) {
    __shared__ float tile[64 * 65];
    int jh = blk & 1, i = (blk >> 1) & 127, b = (blk >> 8) & 3, which = blk >> 10;
    const float* src = which ? x1 : x0;
    _Float16* dst = which ? x1t : x0t;
#pragma unroll
    for (int it = 0; it < 4; it++) {
      int idx = it * 256 + tid;            // 1024 float4 = 64c x 64j
      int c = idx >> 4, j4 = (idx & 15) << 2;
      float4 v = *(const float4*)(src + (size_t)(b * CH + c) * HW + i * WW + jh * 64 + j4);
      *(float4*)&tile[c * 65 + j4] = v;
    }
    __syncthreads();
    int jl = tid >> 2, cq = (tid & 3) << 4;
    _Float16* dp = dst + ((size_t)(b * HP + i + 1) * HP + (jh * 64 + jl + 1)) * CH + cq;
#pragma unroll
    for (int h = 0; h < 2; h++) {
      half8 v;
#pragma unroll
      for (int cc = 0; cc < 8; cc++) v[cc] = (_Float16)tile[(cq + h * 8 + cc) * 65 + jl];
      *(half8*)(dp + h * 8) = v;
    }
    if (tid < 8) {                          // ring column jo=0 (jh0) / jo=129 (jh1)
      int jo = jh ? (HP - 1) : 0;
      _Float16* zp = dst + ((size_t)(b * HP + i + 1) * HP + jo) * CH + tid * 8;
      int4 z = {0, 0, 0, 0};
      *(int4*)zp = z;
    }
  } else if (blk < 2064) {
    int z = blk - 2048;
    int which = z >> 3, b = (z >> 1) & 3, top = z & 1;
    _Float16* dst = (which ? x1t : x0t) + ((size_t)(b * HP + top * (HP - 1)) * HP) * CH;
    int4 zz = {0, 0, 0, 0};
    for (int e = tid; e < 1040; e += 256) *(int4*)((char*)dst + e * 16) = zz;
  } else {
    int gid = (blk - 2064) * 256 + tid;     // 216*256 = 36864 + 18432
    if (gid < 36864) {
      int j = gid & 7, lane = (gid >> 3) & 63, mt = (gid >> 9) & 3, s = gid >> 11;
      int oc = mt * 16 + (lane & 15);
      int t = s * 32 + (lane >> 4) * 8 + j;
      int k = t >> 6, c = t & 63;
      wf[gid] = (_Float16)cw[(oc * CH + c) * 9 + k];
    } else {
      int g = gid - 36864;
      int j = g & 7, lane = (g >> 3) & 63, mt = (g >> 9) & 1, s = g >> 10;
      int o = mt * 16 + (lane & 15);
      int t = s * 32 + (lane >> 4) * 8 + j;
      int k = t >> 6, c = t & 63;
      pf[g] = (o < NOFF) ? (_Float16)pw[(o * CH + c) * 9 + k] : (_Float16)0.f;
    }
  }
}

// ---------------------------------------------------------------------------
// Kernel B: fully fused, verbatim R3 (best measured 113.5 us). Block = 32-px
// strip (b, i, j0), 256 thr, 4 blocks/CU (LDS 40320 B). A-frag reuse across
// n-tiles: each wave owns ONE m-tile, computes BOTH 16-px n-tiles.
// R4 lesson: cooperative fusion of prep+deform regressed 3x (grid.sync spin:
// VALUBusy 3%, dur 267us) - kernel boundary is CHEAPER than in-kernel grid
// sync on 8 non-coherent XCDs. Keep the two-kernel pipeline.
// Phases:
//  0. stage x1t patch (3 rows x 34 cols x 64ch) into btile-aliased LDS.
//  1. offset GEMM: D[o][px], M=32 (18 used), K=576; waves 0-1, A-reuse nt=0,1.
//  1.5 table build: 288 items (32 px x 9 k), weights f16x4 + coords u8x4.
//  2. gather: tid = px*8+cg; 12 B broadcast from tables; 4 coalesced corner
//     loads; packed-f16 interp -> half8 frag -> ds_write_b128.
//  3. main GEMM: D[oc][px], M=64, K=576; wave w = m-tile, A-reuse nt=0,1.
// XCD band swizzle: each XCD owns 64 contiguous rows of one image.
// ---------------------------------------------------------------------------
__global__ __launch_bounds__(256, 4) void deform_all(
    const _Float16* __restrict__ x0t, const _Float16* __restrict__ x1t,
    const _Float16* __restrict__ pf, const float* __restrict__ pb,
    const _Float16* __restrict__ wf, float* __restrict__ out) {
  __shared__ __align__(16) _Float16 btile[2 * 18 * 64 * 8];   // 36864 B (aliased: phase0/1 x1 patch+offs, phase2/3 frag tile)
  __shared__ __align__(16) _Float16 wtab[288 * 4];            // 2304 B: bilinear weights per (px,k)
  __shared__ unsigned ctab[288];                              // 1152 B: packed corner coords per (px,k)
  float* offs = (float*)&btile[12288];    // bytes [24576,27136): dead zone during phases 0/1

  int xcd = blockIdx.x & 7, local = blockIdx.x >> 3;
  int strip = xcd * 256 + local;            // 0..2047
  int jq2 = strip & 3, i = (strip >> 2) & 127, b = strip >> 9;
  int j0 = jq2 * 32;
  int tid = threadIdx.x;
  const _Float16* x0b = x0t + (size_t)b * HP * HP * CH;
  const _Float16* x1b = x1t + (size_t)b * HP * HP * CH;

  // ---- Phase 0: stage x1t patch rows i..i+2, cols j0..j0+33 (coalesced) ----
  {
#pragma unroll
    for (int it = 0; it < 4; it++) {
      int e = it * 256 + tid;               // 816 half8 chunks = 3*34*8
      if (e < 816) {
        int r = e / 272, rem = e - r * 272;
        int col = rem >> 3, cg8 = rem & 7;
        half8 v = *(const half8*)(x1b + ((size_t)(i + r) * HP + (j0 + col)) * CH + cg8 * 8);
        *(half8*)&btile[(r * 34 + col) * 72 + cg8 * 8] = v;
      }
    }
  }
  __syncthreads();

  // ---- Phase 1: offset GEMM (M=32 padded from 18, K=576), A-reuse over nt ----
  {
    int lane = tid & 63, w = tid >> 6;
    if (w < 2) {                            // wave w owns m-tile w; waves 2-3 idle
      int p = lane & 15, q = lane >> 4;
      const half8* pfv = (const half8*)pf;
      f32x4 acc0 = {0.f, 0.f, 0.f, 0.f}, acc1 = {0.f, 0.f, 0.f, 0.f};
#pragma unroll 3
      for (int s = 0; s < 18; s++) {
        int u = 4 * s + q, k = u >> 3, c0 = (u & 7) << 3;   // t = s*32+q*8 -> (k,c)
        int ki = (k * 86) >> 8, kj = k - ki * 3;            // k/3, k%3 for k<9
        half8 a = pfv[(s * 2 + w) * 64 + lane];
        half8 b0 = *(const half8*)&btile[(ki * 34 + p + kj) * 72 + c0];
        half8 b1 = *(const half8*)&btile[(ki * 34 + 16 + p + kj) * 72 + c0];
        acc0 = __builtin_amdgcn_mfma_f32_16x16x32_f16(a, b0, acc0, 0, 0, 0);
        acc1 = __builtin_amdgcn_mfma_f32_16x16x32_f16(a, b1, acc1, 0, 0, 0);
      }
      int col = lane & 15, quad = lane >> 4;
#pragma unroll
      for (int r = 0; r < 4; r++) {
        int o = w * 16 + quad * 4 + r;
        if (o < NOFF) {
          float bias = pb[o];
          offs[col * 20 + o] = acc0[r] + bias;
          offs[(16 + col) * 20 + o] = acc1[r] + bias;
        }
      }
    }
  }
  __syncthreads();

  // ---- Phase 1.5: build interp weight/coord tables, one item per (px,k) ----
  {
    auto build = [&](int px, int k) {
      float ox = offs[px * 20 + k];
      float oy = offs[px * 20 + k + 9];
      int ki = (k * 11) >> 5, kj = k - ki * 3;            // k/3, k%3 for k<9
      float pxr = (float)(i + ki) + ox;                   // padded coords
      float pyr = (float)(j0 + px + kj) + oy;
      float fx = floorf(pxr), fy = floorf(pyr);
      float qltx = fminf(fmaxf(fx, 0.f), 129.f);
      float qlty = fminf(fmaxf(fy, 0.f), 129.f);
      float qrbx = fminf(fmaxf(fx + 1.f, 0.f), 129.f);
      float qrby = fminf(fmaxf(fy + 1.f, 0.f), 129.f);
      float pxc = fminf(fmaxf(pxr, 0.f), 129.f);
      float pyc = fminf(fmaxf(pyr, 0.f), 129.f);
      half4 wv;
      wv[0] = (_Float16)((1.f + qltx - pxc) * (1.f + qlty - pyc));  // lt
      wv[1] = (_Float16)((1.f - qrbx + pxc) * (1.f - qrby + pyc));  // rb
      wv[2] = (_Float16)((1.f + qltx - pxc) * (1.f - qrby + pyc));  // lb
      wv[3] = (_Float16)((1.f - qrbx + pxc) * (1.f + qlty - pyc));  // rt
      *(half4*)&wtab[(px * 9 + k) * 4] = wv;
      ctab[px * 9 + k] = (unsigned)(int)qltx | ((unsigned)(int)qlty << 8) |
                         ((unsigned)(int)qrbx << 16) | ((unsigned)(int)qrby << 24);
    };
    build(tid >> 3, tid & 7);               // items k=0..7 for all 32 px
    if (tid < 32) build(tid, 8);            // items k=8
  }
  __syncthreads();

  // ---- Phase 2: coalesced gather + table-driven interp -> frag btile ----
  {
    int cg8 = tid & 7, px = tid >> 3;       // 32 px x 8 channel-chunks
    int c0 = cg8 * 8;
    int nt = px >> 4, pxl = px & 15, kgq = cg8 & 3, sh = cg8 >> 2;
    _Float16* wslot = &btile[(((nt * 18) * 4 + kgq) * 16 + pxl) * 8];
    const _Float16* xb0 = x0b + c0;
#pragma unroll
    for (int k = 0; k < 9; k++) {
      half4 wv = *(const half4*)&wtab[(px * 9 + k) * 4];   // broadcast across cg
      unsigned cc = ctab[px * 9 + k];
      int ltx = cc & 255, lty = (cc >> 8) & 255;
      int rbx = (cc >> 16) & 255, rby = cc >> 24;
      const _Float16* rowl = xb0 + ltx * (HP * CH);
      const _Float16* rowr = xb0 + rbx * (HP * CH);
      half8 vlt = *(const half8*)(rowl + lty * CH);
      half8 vlb = *(const half8*)(rowl + rby * CH);
      half8 vrb = *(const half8*)(rowr + rby * CH);
      half8 vrt = *(const half8*)(rowr + lty * CH);
      half8 f = vlt * wv[0] + vrb * wv[1] + vlb * wv[2] + vrt * wv[3];
      int s = k * 2 + sh;                   // t = k*64 + c0 + jj -> frag (s,kgq,pxl)
      *(half8*)(wslot + s * 512) = f;       // 512 halfs per s-step
    }
  }
  __syncthreads();

  // ---- Phase 3: main GEMM, D[oc][px], M=64, K=576, A-reuse over nt ----
  {
    int lane = tid & 63, w = tid >> 6;      // wave w = m-tile 0..3
    f32x4 acc0 = {0.f, 0.f, 0.f, 0.f}, acc1 = {0.f, 0.f, 0.f, 0.f};
    const half8* wfv = (const half8*)wf;
    const half8* bt0 = (const half8*)&btile[0];
    const half8* bt1 = (const half8*)&btile[18 * 512];
#pragma unroll 6
    for (int s = 0; s < 18; s++) {
      half8 a = wfv[(s * 4 + w) * 64 + lane];
      acc0 = __builtin_amdgcn_mfma_f32_16x16x32_f16(a, bt0[s * 64 + lane], acc0, 0, 0, 0);
      acc1 = __builtin_amdgcn_mfma_f32_16x16x32_f16(a, bt1[s * 64 + lane], acc1, 0, 0, 0);
    }
    int col = lane & 15, quad = lane >> 4;
#pragma unroll
    for (int r = 0; r < 4; r++) {
      int oc = w * 16 + quad * 4 + r;
      float* orow = out + ((size_t)(b * OC + oc) * HH + i) * WW;
      orow[j0 + col] = acc0[r];
      orow[j0 + 16 + col] = acc1[r];
    }
  }
}

// ---------------------------------------------------------------------------
extern "C" void kernel_launch(void* const* d_in, const int* in_sizes, int n_in,
                              void* d_out, int out_size, void* d_ws, size_t ws_size,
                              hipStream_t stream) {
  const float* x0 = (const float*)d_in[0];
  const float* x1 = (const float*)d_in[1];
  const float* pw = (const float*)d_in[2];
  const float* pb = (const float*)d_in[3];
  const float* cw = (const float*)d_in[4];
  float* out = (float*)d_out;

  _Float16* wfrag  = (_Float16*)((char*)d_ws + WF_OFF);
  _Float16* pwfrag = (_Float16*)((char*)d_ws + PF_OFF);
  _Float16* x0t    = (_Float16*)((char*)d_ws + X0T_OFF);
  _Float16* x1t    = (_Float16*)((char*)d_ws + X1T_OFF);

  prep_all<<<dim3(2280), dim3(256), 0, stream>>>(x0, x1, cw, pw, x0t, x1t, wfrag, pwfrag);
  deform_all<<<dim3(2048), dim3(256), 0, stream>>>(x0t, x1t, pwfrag, pb, wfrag, out);
}